// Round 6
// baseline (660.552 us; speedup 1.0000x reference)
//
#include <hip/hip_runtime.h>
#include <hip/hip_fp16.h>
#include <math.h>

#define NN 50000
#define EE 800000
#define HH 128
#define KIT 10
#define NHF (NN * HH)     // 6,400,000 elements per snapshot
#define PST 16            // atomic-table stride (floats/ints) -> 64B per counter

typedef _Float16 half8 __attribute__((ext_vector_type(8)));
typedef float floatx4 __attribute__((ext_vector_type(4)));

__device__ __forceinline__ float gelu_exact(float x) {
  return 0.5f * x * (1.f + erff(x * 0.70710678118654752f));
}

// typed 4-float load/store helpers (fp32 or fp16 storage)
__device__ __forceinline__ float4 ld4(const float* p) { return *(const float4*)p; }
__device__ __forceinline__ float4 ld4(const __half* p) {
  const __half2* q = (const __half2*)p;
  float2 lo = __half22float2(q[0]);
  float2 hi = __half22float2(q[1]);
  return make_float4(lo.x, lo.y, hi.x, hi.y);
}
__device__ __forceinline__ void st1(float* p, float v) { *p = v; }
__device__ __forceinline__ void st1(__half* p, float v) { *p = __float2half_rn(v); }

// ---------------- graph preprocessing ----------------
// wsum_p/deg_p are padded: one counter per 64B line (index i*PST) to kill
// per-line atomic serialization at the coherence point.
__global__ __launch_bounds__(256) void zero_kernel(float* __restrict__ wsum_p,
                                                   int* __restrict__ deg_p, int n) {
  int i = blockIdx.x * 256 + threadIdx.x;
  if (i < n) { wsum_p[i] = 0.f; deg_p[i] = 0; }
}

// also emits per-edge rank within its destination bucket (removes csr_fill atomic)
__global__ __launch_bounds__(256) void edge_stats_kernel(const int* __restrict__ ei,
                                                         const float* __restrict__ ew,
                                                         float* __restrict__ wsum_p,
                                                         int* __restrict__ deg_p,
                                                         int* __restrict__ rank, int e_cnt) {
  int e = blockIdx.x * 256 + threadIdx.x;
  if (e >= e_cnt) return;
  atomicAdd(&wsum_p[(size_t)ei[e] * PST], ew[e]);            // out-weight sum by source
  rank[e] = atomicAdd(&deg_p[(size_t)ei[EE + e] * PST], 1);  // in-degree by destination
}

// multi-block scan: block sums -> scan partials -> local writeback
__global__ __launch_bounds__(256) void scan1_kernel(const int* __restrict__ deg_p,
                                                    int* __restrict__ bsum, int n) {
  __shared__ int red[256];
  int i = blockIdx.x * 256 + threadIdx.x;
  red[threadIdx.x] = (i < n) ? deg_p[(size_t)i * PST] : 0;
  __syncthreads();
  for (int off = 128; off > 0; off >>= 1) {
    if (threadIdx.x < off) red[threadIdx.x] += red[threadIdx.x + off];
    __syncthreads();
  }
  if (threadIdx.x == 0) bsum[blockIdx.x] = red[0];
}

__global__ __launch_bounds__(256) void scan2_kernel(const int* __restrict__ bsum,
                                                    int* __restrict__ boff,
                                                    int* __restrict__ row_start, int nb, int n) {
  __shared__ int buf[256];
  int tid = threadIdx.x;
  int v = (tid < nb) ? bsum[tid] : 0;
  buf[tid] = v;
  __syncthreads();
  for (int off = 1; off < 256; off <<= 1) {
    int t = (tid >= off) ? buf[tid - off] : 0;
    __syncthreads();
    buf[tid] += t;
    __syncthreads();
  }
  if (tid < nb) boff[tid] = buf[tid] - v;  // exclusive prefix
  if (tid == 255) row_start[n] = buf[255];
}

__global__ __launch_bounds__(256) void scan3_kernel(const int* __restrict__ deg_p,
                                                    const int* __restrict__ boff,
                                                    int* __restrict__ row_start, int n) {
  __shared__ int buf[256];
  int tid = threadIdx.x;
  int i = blockIdx.x * 256 + tid;
  int v = (i < n) ? deg_p[(size_t)i * PST] : 0;
  buf[tid] = v;
  __syncthreads();
  for (int off = 1; off < 256; off <<= 1) {
    int t = (tid >= off) ? buf[tid - off] : 0;
    __syncthreads();
    buf[tid] += t;
    __syncthreads();
  }
  if (i < n) row_start[i] = boff[blockIdx.x] + buf[tid] - v;
}

__global__ __launch_bounds__(256) void csr_fill_kernel(const int* __restrict__ ei,
                                                       const float* __restrict__ ew,
                                                       const float* __restrict__ wsum_p,
                                                       const int* __restrict__ row_start,
                                                       const int* __restrict__ rank,
                                                       int2* __restrict__ csr, int e_cnt) {
  int e = blockIdx.x * 256 + threadIdx.x;
  if (e >= e_cnt) return;
  int r = ei[e], c = ei[EE + e];
  float ws = wsum_p[(size_t)r * PST];
  ws = ws < 1.f ? 1.f : ws;
  float v = 0.9f * ew[e] / ws;            // (1-ALPHA) * enorm folded together
  int pos = row_start[c] + rank[e];       // no atomic
  csr[pos] = make_int2(r, __float_as_int(v));
}

// ---------------- propagation: one wave per node, fp16 h, half2 per lane ----------------
// CSR walked in 8-edge scalar batches, software-pipelined: next batch's s_loads
// issue while current batch's 8 row-gathers are in flight.
__global__ __launch_bounds__(256) void prop_kernel(const __half* __restrict__ h_cur,
                                                   const __half* __restrict__ base,
                                                   const int* __restrict__ row_start,
                                                   const long* __restrict__ csr,
                                                   __half* __restrict__ h_next) {
  int node = __builtin_amdgcn_readfirstlane((int)blockIdx.x * 4 + (int)(threadIdx.x >> 6));
  if (node >= NN) return;
  int lane = threadIdx.x & 63;
  const __half2* hc = (const __half2*)h_cur;
  float2 b = __half22float2(((const __half2*)base)[(size_t)node * 64 + lane]);
  float ax = 0.1f * b.x, ay = 0.1f * b.y;   // ALPHA * base
  float bx = 0.f, by = 0.f;
  int s = row_start[node], e = row_start[node + 1];
  int nfull = (e - s) >> 3;
  int i = s;
  if (nfull > 0) {
    long cur[8];
#pragma unroll
    for (int j = 0; j < 8; ++j) cur[j] = csr[i + j];
    i += 8;
    for (int bidx = 1; bidx < nfull; ++bidx) {
      long nxt[8];
#pragma unroll
      for (int j = 0; j < 8; ++j) nxt[j] = csr[i + j];
      i += 8;
      float2 g[8];
#pragma unroll
      for (int j = 0; j < 8; ++j) g[j] = __half22float2(hc[(size_t)(int)cur[j] * 64 + lane]);
#pragma unroll
      for (int j = 0; j < 8; ++j) {
        float v = __int_as_float((int)(cur[j] >> 32));
        if (j & 1) { bx = fmaf(v, g[j].x, bx); by = fmaf(v, g[j].y, by); }
        else       { ax = fmaf(v, g[j].x, ax); ay = fmaf(v, g[j].y, ay); }
      }
#pragma unroll
      for (int j = 0; j < 8; ++j) cur[j] = nxt[j];
    }
    float2 g[8];
#pragma unroll
    for (int j = 0; j < 8; ++j) g[j] = __half22float2(hc[(size_t)(int)cur[j] * 64 + lane]);
#pragma unroll
    for (int j = 0; j < 8; ++j) {
      float v = __int_as_float((int)(cur[j] >> 32));
      if (j & 1) { bx = fmaf(v, g[j].x, bx); by = fmaf(v, g[j].y, by); }
      else       { ax = fmaf(v, g[j].x, ax); ay = fmaf(v, g[j].y, ay); }
    }
  }
  for (; i < e; ++i) {
    long c0 = csr[i];
    float2 g0 = __half22float2(hc[(size_t)(int)c0 * 64 + lane]);
    float v = __int_as_float((int)(c0 >> 32));
    ax = fmaf(v, g0.x, ax); ay = fmaf(v, g0.y, ay);
  }
  ((__half2*)h_next)[(size_t)node * 64 + lane] =
      __float22half2_rn(make_float2(ax + bx, ay + by));
}

// ---------------- MFMA dense: out[n][j] = act(sum_k X[n][k] * W[j][k] + ...) -------------
template <int K, int KA, int JP, int JR, int ACT, bool RESID, typename IT, typename OT>
__global__ __launch_bounds__(256) void mfma_dense(
    const IT* __restrict__ Xa, const IT* __restrict__ Xb,
    const float* __restrict__ W, const float* __restrict__ lb,
    const float* __restrict__ bg, const float* __restrict__ bb,
    const float* __restrict__ bm, const float* __restrict__ bv,
    const OT* __restrict__ resid, OT* __restrict__ out) {
  constexpr int KC = (K > 128) ? 128 : K;
  static_assert(K % KC == 0 && KC % 32 == 0 && JP % 16 == 0, "");
  constexpr int JT = JP / 16;
  __shared__ _Float16 xL[128][KC + 8];
  __shared__ _Float16 wL[JP][KC + 8];
  const int tid = threadIdx.x;
  const int wv = tid >> 6, lane = tid & 63;
  const int q = lane >> 4, m = lane & 15;
  const int r0 = blockIdx.x * 128;

  floatx4 acc[2][JT];
#pragma unroll
  for (int rt = 0; rt < 2; ++rt)
#pragma unroll
    for (int jt = 0; jt < JT; ++jt) acc[rt][jt] = (floatx4)(0.f);

  for (int kc = 0; kc < K; kc += KC) {
    __syncthreads();
    // stage X: 128 rows x KC cols, fp16
    for (int idx = tid; idx < 128 * (KC / 4); idx += 256) {
      int r = idx / (KC / 4);
      int c4 = (idx % (KC / 4)) * 4;
      int row = r0 + r;
      int col = kc + c4;
      float4 v = make_float4(0.f, 0.f, 0.f, 0.f);
      if (row < NN) {
        if (col < KA) v = ld4(&Xa[(size_t)row * KA + col]);
        else          v = ld4(&Xb[(size_t)row * (K - KA) + (col - KA)]);
      }
      xL[r][c4 + 0] = (_Float16)v.x; xL[r][c4 + 1] = (_Float16)v.y;
      xL[r][c4 + 2] = (_Float16)v.z; xL[r][c4 + 3] = (_Float16)v.w;
    }
    // stage W: JP rows x KC cols, fp16 (zero-fill beyond JR)
    for (int idx = tid; idx < JP * (KC / 4); idx += 256) {
      int j = idx / (KC / 4);
      int c4 = (idx % (KC / 4)) * 4;
      float4 v = make_float4(0.f, 0.f, 0.f, 0.f);
      if (j < JR) v = *(const float4*)&W[(size_t)j * K + kc + c4];
      wL[j][c4 + 0] = (_Float16)v.x; wL[j][c4 + 1] = (_Float16)v.y;
      wL[j][c4 + 2] = (_Float16)v.z; wL[j][c4 + 3] = (_Float16)v.w;
    }
    __syncthreads();
#pragma unroll
    for (int ks = 0; ks < KC; ks += 32) {
      half8 a0 = *(const half8*)&xL[wv * 32 + m][ks + q * 8];
      half8 a1 = *(const half8*)&xL[wv * 32 + 16 + m][ks + q * 8];
#pragma unroll
      for (int jt = 0; jt < JT; ++jt) {
        half8 b = *(const half8*)&wL[jt * 16 + m][ks + q * 8];
        acc[0][jt] = __builtin_amdgcn_mfma_f32_16x16x32_f16(a0, b, acc[0][jt], 0, 0, 0);
        acc[1][jt] = __builtin_amdgcn_mfma_f32_16x16x32_f16(a1, b, acc[1][jt], 0, 0, 0);
      }
    }
  }
  // epilogue: lane holds col j = jt*16 + m, rows q*4 + reg (+16 per rt)
#pragma unroll
  for (int jt = 0; jt < JT; ++jt) {
    int j = jt * 16 + m;
    if (j >= JR) continue;
    float sc = 0.f, sh = 0.f;
    if (ACT == 1) {
      sc = bg[j] * rsqrtf(bv[j] + 1e-5f);
      sh = (lb[j] - bm[j]) * sc + bb[j];
    } else {
      sh = lb[j];
    }
#pragma unroll
    for (int rt = 0; rt < 2; ++rt) {
#pragma unroll
      for (int reg = 0; reg < 4; ++reg) {
        int row = r0 + wv * 32 + rt * 16 + q * 4 + reg;
        if (row >= NN) continue;
        float a = acc[rt][jt][reg];
        float y;
        if (ACT == 0)      y = a + sh;
        else if (ACT == 1) y = fmaxf(fmaf(a, sc, sh), 0.f);
        else               y = gelu_exact(a + sh);
        if (RESID) y += (float)resid[(size_t)row * JR + j];
        st1(&out[(size_t)row * JR + j], y);
      }
    }
  }
}

// ---------------- att2 (64 -> 11) + softmax, one thread per node ----------------
__global__ __launch_bounds__(64) void att2_softmax_kernel(const __half* __restrict__ g,
                                                          const float* __restrict__ W2,
                                                          const float* __restrict__ b2,
                                                          float* __restrict__ attw, int n_rows) {
  __shared__ float gl[64][65];
  int r0 = blockIdx.x * 64;
  for (int idx = threadIdx.x; idx < 64 * 16; idx += 64) {
    int r = idx >> 4, c4 = (idx & 15) * 4;
    float4 v = make_float4(0.f, 0.f, 0.f, 0.f);
    if (r0 + r < n_rows) v = ld4(&g[(size_t)(r0 + r) * 64 + c4]);
    gl[r][c4] = v.x; gl[r][c4 + 1] = v.y; gl[r][c4 + 2] = v.z; gl[r][c4 + 3] = v.w;
  }
  __syncthreads();
  int r = threadIdx.x;
  int n = r0 + r;
  if (n >= n_rows) return;
  float a[KIT + 1];
#pragma unroll
  for (int j = 0; j < KIT + 1; ++j) {
    float acc = b2[j];
#pragma unroll
    for (int k = 0; k < 64; ++k) acc = fmaf(gl[r][k], W2[j * 64 + k], acc);
    a[j] = acc;
  }
  float mx = a[0];
#pragma unroll
  for (int j = 1; j < KIT + 1; ++j) mx = fmaxf(mx, a[j]);
  float s = 0.f;
#pragma unroll
  for (int j = 0; j < KIT + 1; ++j) { a[j] = expf(a[j] - mx); s += a[j]; }
  float inv = 1.f / s;
#pragma unroll
  for (int j = 0; j < KIT + 1; ++j) attw[n * 16 + j] = a[j] * inv;
}

// ---------------- fuse: fused[n][128] = sum_k attw[n][k] * XS_k[n] (fp16) ----------------
__global__ __launch_bounds__(256) void fused_gather_kernel(const __half* __restrict__ XS,
                                                           const float* __restrict__ attw,
                                                           __half* __restrict__ fused) {
  int node = __builtin_amdgcn_readfirstlane((int)blockIdx.x * 4 + (int)(threadIdx.x >> 6));
  if (node >= NN) return;
  int lane = threadIdx.x & 63;
  float ax = 0.f, ay = 0.f;
#pragma unroll
  for (int k = 0; k <= KIT; ++k) {
    float wk = attw[node * 16 + k];   // wave-uniform -> s_load
    float2 v = __half22float2(((const __half2*)(XS + (size_t)k * NHF))[(size_t)node * 64 + lane]);
    ax = fmaf(wk, v.x, ax);
    ay = fmaf(wk, v.y, ay);
  }
  ((__half2*)fused)[(size_t)node * 64 + lane] = __float22half2_rn(make_float2(ax, ay));
}

// recompute-path variant: fused (+)= attw[:,k] * h (h fp16, fused fp32 for accumulation)
__global__ __launch_bounds__(256) void fused_accum_kernel(const __half* __restrict__ h,
                                                          const float* __restrict__ attw,
                                                          float* __restrict__ fused, int k) {
  int node = __builtin_amdgcn_readfirstlane((int)blockIdx.x * 4 + (int)(threadIdx.x >> 6));
  if (node >= NN) return;
  int lane = threadIdx.x & 63;
  float wk = attw[node * 16 + k];
  float2 v = __half22float2(((const __half2*)h)[(size_t)node * 64 + lane]);
  float2 o;
  if (k == 0) {
    o = make_float2(wk * v.x, wk * v.y);
  } else {
    float2 f = ((const float2*)fused)[(size_t)node * 64 + lane];
    o = make_float2(fmaf(wk, v.x, f.x), fmaf(wk, v.y, f.y));
  }
  ((float2*)fused)[(size_t)node * 64 + lane] = o;
}

extern "C" void kernel_launch(void* const* d_in, const int* in_sizes, int n_in,
                              void* d_out, int out_size, void* d_ws, size_t ws_size,
                              hipStream_t stream) {
  (void)in_sizes; (void)n_in; (void)out_size;
  const float* x      = (const float*)d_in[0];
  const int*   ei     = (const int*)d_in[1];
  const float* ew     = (const float*)d_in[2];
  const float* lin1_w = (const float*)d_in[3];
  const float* lin1_b = (const float*)d_in[4];
  const float* bn1_g  = (const float*)d_in[5];
  const float* bn1_b  = (const float*)d_in[6];
  const float* bn1_m  = (const float*)d_in[7];
  const float* bn1_v  = (const float*)d_in[8];
  const float* lin2_w = (const float*)d_in[9];
  const float* lin2_b = (const float*)d_in[10];
  const float* bn2_g  = (const float*)d_in[11];
  const float* bn2_b  = (const float*)d_in[12];
  const float* bn2_m  = (const float*)d_in[13];
  const float* bn2_v  = (const float*)d_in[14];
  const float* att1_w = (const float*)d_in[15];
  const float* att1_b = (const float*)d_in[16];
  const float* att2_w = (const float*)d_in[17];
  const float* att2_b = (const float*)d_in[18];
  const float* head1_w= (const float*)d_in[19];
  const float* head1_b= (const float*)d_in[20];
  const float* bn3_g  = (const float*)d_in[21];
  const float* bn3_b  = (const float*)d_in[22];
  const float* bn3_m  = (const float*)d_in[23];
  const float* bn3_v  = (const float*)d_in[24];
  const float* head2_w= (const float*)d_in[25];
  const float* head2_b= (const float*)d_in[26];
  float* out = (float*)d_out;

  char* p = (char*)d_ws;
  auto alloc = [&](size_t bytes) -> void* {
    void* r = (void*)p;
    p += (bytes + 255) & ~(size_t)255;
    return r;
  };
  // persistent buffers (live across whole launch)
  int*   row_start= (int*)alloc((size_t)(NN + 1) * 4);
  int*   bsum     = (int*)alloc((size_t)256 * 4);
  int*   boff     = (int*)alloc((size_t)256 * 4);
  long*  csr      = (long*)alloc((size_t)EE * 8);
  __half* gbuf    = (__half*)alloc((size_t)NN * 64 * 2);
  float* attw     = (float*)alloc((size_t)NN * 16 * 4);
  __half* h1      = (__half*)alloc((size_t)NHF * 2);
  __half* fusedH  = (__half*)alloc((size_t)NHF * 2);
  __half* zbuf    = (__half*)alloc((size_t)NN * 64 * 2);
  size_t common = (size_t)(p - (char*)d_ws);
  size_t stored_need = common + (size_t)(KIT + 1) * NHF * 2 + 4096;
  bool stored = ws_size >= stored_need;

  // preprocessing temporaries: wsum_p/deg_p (padded, 3.2MB each) + rank (3.2MB).
  // In the stored path they OVERLAY the XS[10] snapshot region (12.8MB), which is
  // dead until the final prop iteration -- all on one stream, so this is safe.
  __half* XS = nullptr;
  float* wsum_p; int* deg_p; int* rank;
  if (stored) {
    XS = (__half*)alloc((size_t)(KIT + 1) * NHF * 2);
    char* ovl = (char*)(XS + (size_t)KIT * NHF);
    wsum_p = (float*)ovl;
    deg_p  = (int*)(ovl + (size_t)NN * PST * 4);
    rank   = (int*)(ovl + 2 * (size_t)NN * PST * 4);
  } else {
    wsum_p = (float*)alloc((size_t)NN * PST * 4);
    deg_p  = (int*)alloc((size_t)NN * PST * 4);
    rank   = (int*)alloc((size_t)EE * 4);
  }

  const int GE  = (EE + 255) / 256;          // edge-parallel grid
  const int GN  = (NN + 255) / 256;          // node-parallel grid (196)
  const int GN0 = (NN * PST + 255) / 256;    // padded-table zero grid
  const int GM  = (NN + 127) / 128;          // mfma dense grid (391)
  const int GP  = (NN + 3) / 4;              // wave-per-node grids (12500)
  const int GA  = (NN + 63) / 64;            // att2 grid

  // graph preprocessing
  zero_kernel<<<GN0, 256, 0, stream>>>(wsum_p, deg_p, NN * PST);
  edge_stats_kernel<<<GE, 256, 0, stream>>>(ei, ew, wsum_p, deg_p, rank, EE);
  scan1_kernel<<<GN, 256, 0, stream>>>(deg_p, bsum, NN);
  scan2_kernel<<<1, 256, 0, stream>>>(bsum, boff, row_start, GN, NN);
  scan3_kernel<<<GN, 256, 0, stream>>>(deg_p, boff, row_start, NN);
  csr_fill_kernel<<<GE, 256, 0, stream>>>(ei, ew, wsum_p, row_start, rank, (int2*)csr, EE);

  if (stored) {
    mfma_dense<128, 128, 128, 128, 1, false, float, __half><<<GM, 256, 0, stream>>>(
        x, (const float*)nullptr, lin1_w, lin1_b, bn1_g, bn1_b, bn1_m, bn1_v, nullptr, h1);
    mfma_dense<128, 128, 128, 128, 1, true, __half, __half><<<GM, 256, 0, stream>>>(
        h1, (const __half*)nullptr, lin2_w, lin2_b, bn2_g, bn2_b, bn2_m, bn2_v, h1, XS);
    for (int k = 0; k < KIT; ++k) {
      prop_kernel<<<GP, 256, 0, stream>>>(XS + (size_t)k * NHF, XS, row_start,
                                          csr, XS + (size_t)(k + 1) * NHF);
    }
    mfma_dense<256, 128, 64, 64, 2, false, __half, __half><<<GM, 256, 0, stream>>>(
        XS, XS + (size_t)KIT * NHF, att1_w, att1_b, nullptr, nullptr, nullptr, nullptr,
        nullptr, gbuf);
    att2_softmax_kernel<<<GA, 64, 0, stream>>>(gbuf, att2_w, att2_b, attw, NN);
    fused_gather_kernel<<<GP, 256, 0, stream>>>(XS, attw, fusedH);
    mfma_dense<128, 128, 64, 64, 1, false, __half, __half><<<GM, 256, 0, stream>>>(
        fusedH, (const __half*)nullptr, head1_w, head1_b, bn3_g, bn3_b, bn3_m, bn3_v,
        nullptr, zbuf);
  } else {
    float*  fusedF = (float*)alloc((size_t)NHF * 4);
    __half* base   = (__half*)alloc((size_t)NHF * 2);
    __half* hA     = (__half*)alloc((size_t)NHF * 2);
    __half* hB     = (__half*)alloc((size_t)NHF * 2);
    mfma_dense<128, 128, 128, 128, 1, false, float, __half><<<GM, 256, 0, stream>>>(
        x, (const float*)nullptr, lin1_w, lin1_b, bn1_g, bn1_b, bn1_m, bn1_v, nullptr, h1);
    mfma_dense<128, 128, 128, 128, 1, true, __half, __half><<<GM, 256, 0, stream>>>(
        h1, (const __half*)nullptr, lin2_w, lin2_b, bn2_g, bn2_b, bn2_m, bn2_v, h1, base);
    // pass 1: get xs10
    const __half* cur = base;
    for (int k = 1; k <= KIT; ++k) {
      __half* nxt = (k & 1) ? hA : hB;
      prop_kernel<<<GP, 256, 0, stream>>>(cur, base, row_start, csr, nxt);
      cur = nxt;
    }
    mfma_dense<256, 128, 64, 64, 2, false, __half, __half><<<GM, 256, 0, stream>>>(
        base, cur, att1_w, att1_b, nullptr, nullptr, nullptr, nullptr, nullptr, gbuf);
    att2_softmax_kernel<<<GA, 64, 0, stream>>>(gbuf, att2_w, att2_b, attw, NN);
    // pass 2: re-propagate, accumulate fused on the fly (fp32 accumulator)
    fused_accum_kernel<<<GP, 256, 0, stream>>>(base, attw, fusedF, 0);
    cur = base;
    for (int k = 1; k <= KIT; ++k) {
      __half* nxt = (k & 1) ? hA : hB;
      prop_kernel<<<GP, 256, 0, stream>>>(cur, base, row_start, csr, nxt);
      fused_accum_kernel<<<GP, 256, 0, stream>>>(nxt, attw, fusedF, k);
      cur = nxt;
    }
    mfma_dense<128, 128, 64, 64, 1, false, float, __half><<<GM, 256, 0, stream>>>(
        fusedF, (const float*)nullptr, head1_w, head1_b, bn3_g, bn3_b, bn3_m, bn3_v,
        nullptr, zbuf);
  }

  // head2 (z fp16 -> out fp32)
  mfma_dense<64, 64, 48, 40, 0, false, __half, float><<<GM, 256, 0, stream>>>(
      zbuf, (const __half*)nullptr, head2_w, head2_b, nullptr, nullptr, nullptr, nullptr,
      nullptr, out);
}

// Round 7
// 628.770 us; speedup vs baseline: 1.0505x; 1.0505x over previous
//
#include <hip/hip_runtime.h>
#include <hip/hip_fp16.h>
#include <math.h>

#define NN 50000
#define EE 800000
#define HH 128
#define KIT 10
#define NHF (NN * HH)     // 6,400,000 elements per snapshot
#define RR 8              // node ranges for LDS histogram
#define CC 64             // edge chunks
#define NR (NN / RR)      // 6250 nodes per range
#define CH (EE / CC)      // 12500 edges per chunk

typedef _Float16 half8 __attribute__((ext_vector_type(8)));
typedef float floatx4 __attribute__((ext_vector_type(4)));

__device__ __forceinline__ float gelu_exact(float x) {
  return 0.5f * x * (1.f + erff(x * 0.70710678118654752f));
}

// typed 4-float load/store helpers (fp32 or fp16 storage)
__device__ __forceinline__ float4 ld4(const float* p) { return *(const float4*)p; }
__device__ __forceinline__ float4 ld4(const __half* p) {
  const __half2* q = (const __half2*)p;
  float2 lo = __half22float2(q[0]);
  float2 hi = __half22float2(q[1]);
  return make_float4(lo.x, lo.y, hi.x, hi.y);
}
__device__ __forceinline__ void st1(float* p, float v) { *p = v; }
__device__ __forceinline__ void st1(__half* p, float v) { *p = __float2half_rn(v); }

// ---------------- graph preprocessing (NO global atomics) ----------------
// Block (c, r): LDS-histogram chunk c's edges over node range r.
// hist atomicAdd return value = within-chunk rank of that edge at its dest.
__global__ __launch_bounds__(256) void hist_kernel(const int* __restrict__ ei,
                                                   const float* __restrict__ ew,
                                                   int* __restrict__ pdeg,
                                                   float* __restrict__ pwsum,
                                                   int* __restrict__ rank) {
  __shared__ int hist[NR];
  __shared__ float whist[NR];
  const int c = blockIdx.x, r = blockIdx.y;
  const int lo = r * NR;
  for (int i = threadIdx.x; i < NR; i += 256) { hist[i] = 0; whist[i] = 0.f; }
  __syncthreads();
  const int e0 = c * CH;
  for (int i = threadIdx.x; i < CH; i += 256) {
    int e = e0 + i;
    int src = ei[e], dst = ei[EE + e];
    unsigned us = (unsigned)(src - lo), ud = (unsigned)(dst - lo);
    if (us < NR) atomicAdd(&whist[us], ew[e]);
    if (ud < NR) rank[e] = atomicAdd(&hist[ud], 1);
  }
  __syncthreads();
  for (int i = threadIdx.x; i < NR; i += 256) {
    pdeg [(size_t)c * NN + lo + i] = hist[i];
    pwsum[(size_t)c * NN + lo + i] = whist[i];
  }
}

// per-node: deg = sum over chunks (pdeg -> in-place exclusive chunk prefix),
// wsum = sum over chunks; also block-reduce deg -> bsum (replaces old scan1).
__global__ __launch_bounds__(256) void reduce_kernel(int* __restrict__ pdeg,
                                                     const float* __restrict__ pwsum,
                                                     int* __restrict__ deg,
                                                     float* __restrict__ wsum,
                                                     int* __restrict__ bsum) {
  int node = blockIdx.x * 256 + threadIdx.x;
  int acc = 0; float wacc = 0.f;
  if (node < NN) {
    for (int c = 0; c < CC; ++c) {
      size_t idx = (size_t)c * NN + node;
      int t = pdeg[idx];
      pdeg[idx] = acc;        // exclusive prefix over chunks
      acc += t;
      wacc += pwsum[idx];
    }
    deg[node] = acc;
    wsum[node] = wacc;
  }
  __shared__ int red[256];
  red[threadIdx.x] = (node < NN) ? acc : 0;
  __syncthreads();
  for (int off = 128; off > 0; off >>= 1) {
    if (threadIdx.x < off) red[threadIdx.x] += red[threadIdx.x + off];
    __syncthreads();
  }
  if (threadIdx.x == 0) bsum[blockIdx.x] = red[0];
}

__global__ __launch_bounds__(256) void scan2_kernel(const int* __restrict__ bsum,
                                                    int* __restrict__ boff,
                                                    int* __restrict__ row_start, int nb, int n) {
  __shared__ int buf[256];
  int tid = threadIdx.x;
  int v = (tid < nb) ? bsum[tid] : 0;
  buf[tid] = v;
  __syncthreads();
  for (int off = 1; off < 256; off <<= 1) {
    int t = (tid >= off) ? buf[tid - off] : 0;
    __syncthreads();
    buf[tid] += t;
    __syncthreads();
  }
  if (tid < nb) boff[tid] = buf[tid] - v;  // exclusive prefix
  if (tid == 255) row_start[n] = buf[255];
}

__global__ __launch_bounds__(256) void scan3_kernel(const int* __restrict__ deg,
                                                    const int* __restrict__ boff,
                                                    int* __restrict__ row_start, int n) {
  __shared__ int buf[256];
  int tid = threadIdx.x;
  int i = blockIdx.x * 256 + tid;
  int v = (i < n) ? deg[i] : 0;
  buf[tid] = v;
  __syncthreads();
  for (int off = 1; off < 256; off <<= 1) {
    int t = (tid >= off) ? buf[tid - off] : 0;
    __syncthreads();
    buf[tid] += t;
    __syncthreads();
  }
  if (i < n) row_start[i] = boff[blockIdx.x] + buf[tid] - v;
}

__global__ __launch_bounds__(256) void csr_fill_kernel(const int* __restrict__ ei,
                                                       const float* __restrict__ ew,
                                                       const float* __restrict__ wsum,
                                                       const int* __restrict__ row_start,
                                                       const int* __restrict__ pdeg_excl,
                                                       const int* __restrict__ rank,
                                                       int2* __restrict__ csr, int e_cnt) {
  int e = blockIdx.x * 256 + threadIdx.x;
  if (e >= e_cnt) return;
  int c = e / CH;
  int src = ei[e], dst = ei[EE + e];
  float ws = wsum[src];
  ws = ws < 1.f ? 1.f : ws;
  float v = 0.9f * ew[e] / ws;            // (1-ALPHA) * enorm folded together
  int pos = row_start[dst] + pdeg_excl[(size_t)c * NN + dst] + rank[e];
  csr[pos] = make_int2(src, __float_as_int(v));
}

// ---------------- propagation: one wave per node, fp16 h, half2 per lane ----------------
// CSR walked in 8-edge scalar batches, software-pipelined: next batch's s_loads
// issue while current batch's 8 row-gathers are in flight.
__global__ __launch_bounds__(256) void prop_kernel(const __half* __restrict__ h_cur,
                                                   const __half* __restrict__ base,
                                                   const int* __restrict__ row_start,
                                                   const long* __restrict__ csr,
                                                   __half* __restrict__ h_next) {
  int node = __builtin_amdgcn_readfirstlane((int)blockIdx.x * 4 + (int)(threadIdx.x >> 6));
  if (node >= NN) return;
  int lane = threadIdx.x & 63;
  const __half2* hc = (const __half2*)h_cur;
  float2 b = __half22float2(((const __half2*)base)[(size_t)node * 64 + lane]);
  float ax = 0.1f * b.x, ay = 0.1f * b.y;   // ALPHA * base
  float bx = 0.f, by = 0.f;
  int s = row_start[node], e = row_start[node + 1];
  int nfull = (e - s) >> 3;
  int i = s;
  if (nfull > 0) {
    long cur[8];
#pragma unroll
    for (int j = 0; j < 8; ++j) cur[j] = csr[i + j];
    i += 8;
    for (int bidx = 1; bidx < nfull; ++bidx) {
      long nxt[8];
#pragma unroll
      for (int j = 0; j < 8; ++j) nxt[j] = csr[i + j];
      i += 8;
      float2 g[8];
#pragma unroll
      for (int j = 0; j < 8; ++j) g[j] = __half22float2(hc[(size_t)(int)cur[j] * 64 + lane]);
#pragma unroll
      for (int j = 0; j < 8; ++j) {
        float v = __int_as_float((int)(cur[j] >> 32));
        if (j & 1) { bx = fmaf(v, g[j].x, bx); by = fmaf(v, g[j].y, by); }
        else       { ax = fmaf(v, g[j].x, ax); ay = fmaf(v, g[j].y, ay); }
      }
#pragma unroll
      for (int j = 0; j < 8; ++j) cur[j] = nxt[j];
    }
    float2 g[8];
#pragma unroll
    for (int j = 0; j < 8; ++j) g[j] = __half22float2(hc[(size_t)(int)cur[j] * 64 + lane]);
#pragma unroll
    for (int j = 0; j < 8; ++j) {
      float v = __int_as_float((int)(cur[j] >> 32));
      if (j & 1) { bx = fmaf(v, g[j].x, bx); by = fmaf(v, g[j].y, by); }
      else       { ax = fmaf(v, g[j].x, ax); ay = fmaf(v, g[j].y, ay); }
    }
  }
  for (; i < e; ++i) {
    long c0 = csr[i];
    float2 g0 = __half22float2(hc[(size_t)(int)c0 * 64 + lane]);
    float v = __int_as_float((int)(c0 >> 32));
    ax = fmaf(v, g0.x, ax); ay = fmaf(v, g0.y, ay);
  }
  ((__half2*)h_next)[(size_t)node * 64 + lane] =
      __float22half2_rn(make_float2(ax + bx, ay + by));
}

// ---------------- MFMA dense: out[n][j] = act(sum_k X[n][k] * W[j][k] + ...) -------------
template <int K, int KA, int JP, int JR, int ACT, bool RESID, typename IT, typename OT>
__global__ __launch_bounds__(256) void mfma_dense(
    const IT* __restrict__ Xa, const IT* __restrict__ Xb,
    const float* __restrict__ W, const float* __restrict__ lb,
    const float* __restrict__ bg, const float* __restrict__ bb,
    const float* __restrict__ bm, const float* __restrict__ bv,
    const OT* __restrict__ resid, OT* __restrict__ out) {
  constexpr int KC = (K > 128) ? 128 : K;
  static_assert(K % KC == 0 && KC % 32 == 0 && JP % 16 == 0, "");
  constexpr int JT = JP / 16;
  __shared__ _Float16 xL[128][KC + 8];
  __shared__ _Float16 wL[JP][KC + 8];
  const int tid = threadIdx.x;
  const int wv = tid >> 6, lane = tid & 63;
  const int q = lane >> 4, m = lane & 15;
  const int r0 = blockIdx.x * 128;

  floatx4 acc[2][JT];
#pragma unroll
  for (int rt = 0; rt < 2; ++rt)
#pragma unroll
    for (int jt = 0; jt < JT; ++jt) acc[rt][jt] = (floatx4)(0.f);

  for (int kc = 0; kc < K; kc += KC) {
    __syncthreads();
    // stage X: 128 rows x KC cols, fp16
    for (int idx = tid; idx < 128 * (KC / 4); idx += 256) {
      int r = idx / (KC / 4);
      int c4 = (idx % (KC / 4)) * 4;
      int row = r0 + r;
      int col = kc + c4;
      float4 v = make_float4(0.f, 0.f, 0.f, 0.f);
      if (row < NN) {
        if (col < KA) v = ld4(&Xa[(size_t)row * KA + col]);
        else          v = ld4(&Xb[(size_t)row * (K - KA) + (col - KA)]);
      }
      xL[r][c4 + 0] = (_Float16)v.x; xL[r][c4 + 1] = (_Float16)v.y;
      xL[r][c4 + 2] = (_Float16)v.z; xL[r][c4 + 3] = (_Float16)v.w;
    }
    // stage W: JP rows x KC cols, fp16 (zero-fill beyond JR)
    for (int idx = tid; idx < JP * (KC / 4); idx += 256) {
      int j = idx / (KC / 4);
      int c4 = (idx % (KC / 4)) * 4;
      float4 v = make_float4(0.f, 0.f, 0.f, 0.f);
      if (j < JR) v = *(const float4*)&W[(size_t)j * K + kc + c4];
      wL[j][c4 + 0] = (_Float16)v.x; wL[j][c4 + 1] = (_Float16)v.y;
      wL[j][c4 + 2] = (_Float16)v.z; wL[j][c4 + 3] = (_Float16)v.w;
    }
    __syncthreads();
#pragma unroll
    for (int ks = 0; ks < KC; ks += 32) {
      half8 a0 = *(const half8*)&xL[wv * 32 + m][ks + q * 8];
      half8 a1 = *(const half8*)&xL[wv * 32 + 16 + m][ks + q * 8];
#pragma unroll
      for (int jt = 0; jt < JT; ++jt) {
        half8 b = *(const half8*)&wL[jt * 16 + m][ks + q * 8];
        acc[0][jt] = __builtin_amdgcn_mfma_f32_16x16x32_f16(a0, b, acc[0][jt], 0, 0, 0);
        acc[1][jt] = __builtin_amdgcn_mfma_f32_16x16x32_f16(a1, b, acc[1][jt], 0, 0, 0);
      }
    }
  }
  // epilogue: lane holds col j = jt*16 + m, rows q*4 + reg (+16 per rt)
#pragma unroll
  for (int jt = 0; jt < JT; ++jt) {
    int j = jt * 16 + m;
    if (j >= JR) continue;
    float sc = 0.f, sh = 0.f;
    if (ACT == 1) {
      sc = bg[j] * rsqrtf(bv[j] + 1e-5f);
      sh = (lb[j] - bm[j]) * sc + bb[j];
    } else {
      sh = lb[j];
    }
#pragma unroll
    for (int rt = 0; rt < 2; ++rt) {
#pragma unroll
      for (int reg = 0; reg < 4; ++reg) {
        int row = r0 + wv * 32 + rt * 16 + q * 4 + reg;
        if (row >= NN) continue;
        float a = acc[rt][jt][reg];
        float y;
        if (ACT == 0)      y = a + sh;
        else if (ACT == 1) y = fmaxf(fmaf(a, sc, sh), 0.f);
        else               y = gelu_exact(a + sh);
        if (RESID) y += (float)resid[(size_t)row * JR + j];
        st1(&out[(size_t)row * JR + j], y);
      }
    }
  }
}

// ---------------- att2 (64 -> 11) + softmax, one thread per node ----------------
__global__ __launch_bounds__(64) void att2_softmax_kernel(const __half* __restrict__ g,
                                                          const float* __restrict__ W2,
                                                          const float* __restrict__ b2,
                                                          float* __restrict__ attw, int n_rows) {
  __shared__ float gl[64][65];
  int r0 = blockIdx.x * 64;
  for (int idx = threadIdx.x; idx < 64 * 16; idx += 64) {
    int r = idx >> 4, c4 = (idx & 15) * 4;
    float4 v = make_float4(0.f, 0.f, 0.f, 0.f);
    if (r0 + r < n_rows) v = ld4(&g[(size_t)(r0 + r) * 64 + c4]);
    gl[r][c4] = v.x; gl[r][c4 + 1] = v.y; gl[r][c4 + 2] = v.z; gl[r][c4 + 3] = v.w;
  }
  __syncthreads();
  int r = threadIdx.x;
  int n = r0 + r;
  if (n >= n_rows) return;
  float a[KIT + 1];
#pragma unroll
  for (int j = 0; j < KIT + 1; ++j) {
    float acc = b2[j];
#pragma unroll
    for (int k = 0; k < 64; ++k) acc = fmaf(gl[r][k], W2[j * 64 + k], acc);
    a[j] = acc;
  }
  float mx = a[0];
#pragma unroll
  for (int j = 1; j < KIT + 1; ++j) mx = fmaxf(mx, a[j]);
  float s = 0.f;
#pragma unroll
  for (int j = 0; j < KIT + 1; ++j) { a[j] = expf(a[j] - mx); s += a[j]; }
  float inv = 1.f / s;
#pragma unroll
  for (int j = 0; j < KIT + 1; ++j) attw[n * 16 + j] = a[j] * inv;
}

// ---------------- fuse: fused[n][128] = sum_k attw[n][k] * XS_k[n] (fp16) ----------------
__global__ __launch_bounds__(256) void fused_gather_kernel(const __half* __restrict__ XS,
                                                           const float* __restrict__ attw,
                                                           __half* __restrict__ fused) {
  int node = __builtin_amdgcn_readfirstlane((int)blockIdx.x * 4 + (int)(threadIdx.x >> 6));
  if (node >= NN) return;
  int lane = threadIdx.x & 63;
  float ax = 0.f, ay = 0.f;
#pragma unroll
  for (int k = 0; k <= KIT; ++k) {
    float wk = attw[node * 16 + k];   // wave-uniform -> s_load
    float2 v = __half22float2(((const __half2*)(XS + (size_t)k * NHF))[(size_t)node * 64 + lane]);
    ax = fmaf(wk, v.x, ax);
    ay = fmaf(wk, v.y, ay);
  }
  ((__half2*)fused)[(size_t)node * 64 + lane] = __float22half2_rn(make_float2(ax, ay));
}

// recompute-path variant: fused (+)= attw[:,k] * h (h fp16, fused fp32 for accumulation)
__global__ __launch_bounds__(256) void fused_accum_kernel(const __half* __restrict__ h,
                                                          const float* __restrict__ attw,
                                                          float* __restrict__ fused, int k) {
  int node = __builtin_amdgcn_readfirstlane((int)blockIdx.x * 4 + (int)(threadIdx.x >> 6));
  if (node >= NN) return;
  int lane = threadIdx.x & 63;
  float wk = attw[node * 16 + k];
  float2 v = __half22float2(((const __half2*)h)[(size_t)node * 64 + lane]);
  float2 o;
  if (k == 0) {
    o = make_float2(wk * v.x, wk * v.y);
  } else {
    float2 f = ((const float2*)fused)[(size_t)node * 64 + lane];
    o = make_float2(fmaf(wk, v.x, f.x), fmaf(wk, v.y, f.y));
  }
  ((float2*)fused)[(size_t)node * 64 + lane] = o;
}

extern "C" void kernel_launch(void* const* d_in, const int* in_sizes, int n_in,
                              void* d_out, int out_size, void* d_ws, size_t ws_size,
                              hipStream_t stream) {
  (void)in_sizes; (void)n_in; (void)out_size;
  const float* x      = (const float*)d_in[0];
  const int*   ei     = (const int*)d_in[1];
  const float* ew     = (const float*)d_in[2];
  const float* lin1_w = (const float*)d_in[3];
  const float* lin1_b = (const float*)d_in[4];
  const float* bn1_g  = (const float*)d_in[5];
  const float* bn1_b  = (const float*)d_in[6];
  const float* bn1_m  = (const float*)d_in[7];
  const float* bn1_v  = (const float*)d_in[8];
  const float* lin2_w = (const float*)d_in[9];
  const float* lin2_b = (const float*)d_in[10];
  const float* bn2_g  = (const float*)d_in[11];
  const float* bn2_b  = (const float*)d_in[12];
  const float* bn2_m  = (const float*)d_in[13];
  const float* bn2_v  = (const float*)d_in[14];
  const float* att1_w = (const float*)d_in[15];
  const float* att1_b = (const float*)d_in[16];
  const float* att2_w = (const float*)d_in[17];
  const float* att2_b = (const float*)d_in[18];
  const float* head1_w= (const float*)d_in[19];
  const float* head1_b= (const float*)d_in[20];
  const float* bn3_g  = (const float*)d_in[21];
  const float* bn3_b  = (const float*)d_in[22];
  const float* bn3_m  = (const float*)d_in[23];
  const float* bn3_v  = (const float*)d_in[24];
  const float* head2_w= (const float*)d_in[25];
  const float* head2_b= (const float*)d_in[26];
  float* out = (float*)d_out;

  char* p = (char*)d_ws;
  auto alloc = [&](size_t bytes) -> void* {
    void* r = (void*)p;
    p += (bytes + 255) & ~(size_t)255;
    return r;
  };
  // persistent buffers (live across whole launch)
  int*   row_start= (int*)alloc((size_t)(NN + 1) * 4);
  int*   bsum     = (int*)alloc((size_t)256 * 4);
  int*   boff     = (int*)alloc((size_t)256 * 4);
  int*   deg      = (int*)alloc((size_t)NN * 4);
  float* wsum     = (float*)alloc((size_t)NN * 4);
  long*  csr      = (long*)alloc((size_t)EE * 8);
  __half* gbuf    = (__half*)alloc((size_t)NN * 64 * 2);
  float* attw     = (float*)alloc((size_t)NN * 16 * 4);
  __half* h1      = (__half*)alloc((size_t)NHF * 2);
  __half* fusedH  = (__half*)alloc((size_t)NHF * 2);
  __half* zbuf    = (__half*)alloc((size_t)NN * 64 * 2);
  size_t common = (size_t)(p - (char*)d_ws);
  size_t stored_need = common + (size_t)(KIT + 1) * NHF * 2 + 4096;
  bool stored = ws_size >= stored_need;

  // preprocessing temporaries: pdeg (12.8MB) + pwsum (12.8MB) + rank (3.2MB).
  // In the stored path they OVERLAY the XS[8..10] snapshot region (38.4MB), which
  // is dead until prop iteration k=7 -- all on one stream, so this is safe.
  __half* XS = nullptr;
  int* pdeg; float* pwsum; int* rank;
  if (stored) {
    XS = (__half*)alloc((size_t)(KIT + 1) * NHF * 2);
    char* ovl = (char*)(XS + (size_t)8 * NHF);
    pdeg  = (int*)ovl;
    pwsum = (float*)(ovl + (size_t)CC * NN * 4);
    rank  = (int*)(ovl + 2 * (size_t)CC * NN * 4);
  } else {
    pdeg  = (int*)alloc((size_t)CC * NN * 4);
    pwsum = (float*)alloc((size_t)CC * NN * 4);
    rank  = (int*)alloc((size_t)EE * 4);
  }

  const int GE  = (EE + 255) / 256;          // edge-parallel grid
  const int GN  = (NN + 255) / 256;          // node-parallel grid (196)
  const int GM  = (NN + 127) / 128;          // mfma dense grid (391)
  const int GP  = (NN + 3) / 4;              // wave-per-node grids (12500)
  const int GA  = (NN + 63) / 64;            // att2 grid

  // graph preprocessing (atomic-free)
  hist_kernel<<<dim3(CC, RR), 256, 0, stream>>>(ei, ew, pdeg, pwsum, rank);
  reduce_kernel<<<GN, 256, 0, stream>>>(pdeg, pwsum, deg, wsum, bsum);
  scan2_kernel<<<1, 256, 0, stream>>>(bsum, boff, row_start, GN, NN);
  scan3_kernel<<<GN, 256, 0, stream>>>(deg, boff, row_start, NN);
  csr_fill_kernel<<<GE, 256, 0, stream>>>(ei, ew, wsum, row_start, pdeg, rank,
                                          (int2*)csr, EE);

  if (stored) {
    mfma_dense<128, 128, 128, 128, 1, false, float, __half><<<GM, 256, 0, stream>>>(
        x, (const float*)nullptr, lin1_w, lin1_b, bn1_g, bn1_b, bn1_m, bn1_v, nullptr, h1);
    mfma_dense<128, 128, 128, 128, 1, true, __half, __half><<<GM, 256, 0, stream>>>(
        h1, (const __half*)nullptr, lin2_w, lin2_b, bn2_g, bn2_b, bn2_m, bn2_v, h1, XS);
    for (int k = 0; k < KIT; ++k) {
      prop_kernel<<<GP, 256, 0, stream>>>(XS + (size_t)k * NHF, XS, row_start,
                                          csr, XS + (size_t)(k + 1) * NHF);
    }
    mfma_dense<256, 128, 64, 64, 2, false, __half, __half><<<GM, 256, 0, stream>>>(
        XS, XS + (size_t)KIT * NHF, att1_w, att1_b, nullptr, nullptr, nullptr, nullptr,
        nullptr, gbuf);
    att2_softmax_kernel<<<GA, 64, 0, stream>>>(gbuf, att2_w, att2_b, attw, NN);
    fused_gather_kernel<<<GP, 256, 0, stream>>>(XS, attw, fusedH);
    mfma_dense<128, 128, 64, 64, 1, false, __half, __half><<<GM, 256, 0, stream>>>(
        fusedH, (const __half*)nullptr, head1_w, head1_b, bn3_g, bn3_b, bn3_m, bn3_v,
        nullptr, zbuf);
  } else {
    float*  fusedF = (float*)alloc((size_t)NHF * 4);
    __half* base   = (__half*)alloc((size_t)NHF * 2);
    __half* hA     = (__half*)alloc((size_t)NHF * 2);
    __half* hB     = (__half*)alloc((size_t)NHF * 2);
    mfma_dense<128, 128, 128, 128, 1, false, float, __half><<<GM, 256, 0, stream>>>(
        x, (const float*)nullptr, lin1_w, lin1_b, bn1_g, bn1_b, bn1_m, bn1_v, nullptr, h1);
    mfma_dense<128, 128, 128, 128, 1, true, __half, __half><<<GM, 256, 0, stream>>>(
        h1, (const __half*)nullptr, lin2_w, lin2_b, bn2_g, bn2_b, bn2_m, bn2_v, h1, base);
    // pass 1: get xs10
    const __half* cur = base;
    for (int k = 1; k <= KIT; ++k) {
      __half* nxt = (k & 1) ? hA : hB;
      prop_kernel<<<GP, 256, 0, stream>>>(cur, base, row_start, csr, nxt);
      cur = nxt;
    }
    mfma_dense<256, 128, 64, 64, 2, false, __half, __half><<<GM, 256, 0, stream>>>(
        base, cur, att1_w, att1_b, nullptr, nullptr, nullptr, nullptr, nullptr, gbuf);
    att2_softmax_kernel<<<GA, 64, 0, stream>>>(gbuf, att2_w, att2_b, attw, NN);
    // pass 2: re-propagate, accumulate fused on the fly (fp32 accumulator)
    fused_accum_kernel<<<GP, 256, 0, stream>>>(base, attw, fusedF, 0);
    cur = base;
    for (int k = 1; k <= KIT; ++k) {
      __half* nxt = (k & 1) ? hA : hB;
      prop_kernel<<<GP, 256, 0, stream>>>(cur, base, row_start, csr, nxt);
      fused_accum_kernel<<<GP, 256, 0, stream>>>(nxt, attw, fusedF, k);
      cur = nxt;
    }
    mfma_dense<128, 128, 64, 64, 1, false, float, __half><<<GM, 256, 0, stream>>>(
        fusedF, (const float*)nullptr, head1_w, head1_b, bn3_g, bn3_b, bn3_m, bn3_v,
        nullptr, zbuf);
  }

  // head2 (z fp16 -> out fp32)
  mfma_dense<64, 64, 48, 40, 0, false, __half, float><<<GM, 256, 0, stream>>>(
      zbuf, (const __half*)nullptr, head2_w, head2_b, nullptr, nullptr, nullptr, nullptr,
      nullptr, out);
}

// Round 9
// 598.037 us; speedup vs baseline: 1.1045x; 1.0514x over previous
//
#include <hip/hip_runtime.h>
#include <hip/hip_fp16.h>
#include <math.h>

#define NN 50000
#define EE 800000
#define HH 128
#define KIT 10
#define NHF (NN * HH)     // 6,400,000 elements per snapshot
#define CC 64             // edge chunks
#define CH 12500          // edges per chunk (divisible by 4; byte offset 16B-aligned)
#define RRH 4             // node ranges per mode
#define NRH 12500         // nodes per range (50KB LDS)

typedef _Float16 half8 __attribute__((ext_vector_type(8)));
typedef float floatx4 __attribute__((ext_vector_type(4)));

__device__ __forceinline__ float gelu_exact(float x) {
  return 0.5f * x * (1.f + erff(x * 0.70710678118654752f));
}

// typed 4-float load/store helpers (fp32 or fp16 storage)
__device__ __forceinline__ float4 ld4(const float* p) { return *(const float4*)p; }
__device__ __forceinline__ float4 ld4(const __half* p) {
  const __half2* q = (const __half2*)p;
  float2 lo = __half22float2(q[0]);
  float2 hi = __half22float2(q[1]);
  return make_float4(lo.x, lo.y, hi.x, hi.y);
}
__device__ __forceinline__ void st1(float* p, float v) { *p = v; }
__device__ __forceinline__ void st1(__half* p, float v) { *p = __float2half_rn(v); }

// ---------------- graph preprocessing (NO global atomics) ----------------
// Block (c, z): z<RRH  -> in-degree histogram (+rank) of chunk c over node range z;
//              z>=RRH -> source-weight-sum histogram over range z-RRH.
// One 50KB LDS array per block; edges read as int4/float4 (4 edges/thread-iter).
__global__ __launch_bounds__(256) void hist2_kernel(const int* __restrict__ ei,
                                                    const float* __restrict__ ew,
                                                    int* __restrict__ pdeg,
                                                    float* __restrict__ pwsum,
                                                    int* __restrict__ rank) {
  __shared__ int hist[NRH];
  const int c = blockIdx.x;
  const int z = blockIdx.y;
  const bool isdeg = (z < RRH);
  const int lo = (isdeg ? z : z - RRH) * NRH;
  for (int i = threadIdx.x; i < NRH; i += 256) hist[i] = 0;   // 0 bits == 0.f
  __syncthreads();
  const int e0 = c * CH;
  if (isdeg) {
    const int4* d4 = (const int4*)(ei + (size_t)EE + e0);
    for (int i = threadIdx.x; i < CH / 4; i += 256) {
      int4 d = d4[i];
      int e = e0 + i * 4;
      unsigned u0 = (unsigned)(d.x - lo), u1 = (unsigned)(d.y - lo);
      unsigned u2 = (unsigned)(d.z - lo), u3 = (unsigned)(d.w - lo);
      if (u0 < NRH) rank[e]     = atomicAdd(&hist[u0], 1);
      if (u1 < NRH) rank[e + 1] = atomicAdd(&hist[u1], 1);
      if (u2 < NRH) rank[e + 2] = atomicAdd(&hist[u2], 1);
      if (u3 < NRH) rank[e + 3] = atomicAdd(&hist[u3], 1);
    }
    __syncthreads();
    for (int i = threadIdx.x; i < NRH; i += 256)
      pdeg[(size_t)c * NN + lo + i] = hist[i];
  } else {
    float* whist = (float*)hist;
    const int4* s4 = (const int4*)(ei + e0);
    const float4* w4 = (const float4*)(ew + e0);
    for (int i = threadIdx.x; i < CH / 4; i += 256) {
      int4 s = s4[i];
      float4 w = w4[i];
      unsigned u0 = (unsigned)(s.x - lo), u1 = (unsigned)(s.y - lo);
      unsigned u2 = (unsigned)(s.z - lo), u3 = (unsigned)(s.w - lo);
      if (u0 < NRH) atomicAdd(&whist[u0], w.x);
      if (u1 < NRH) atomicAdd(&whist[u1], w.y);
      if (u2 < NRH) atomicAdd(&whist[u2], w.z);
      if (u3 < NRH) atomicAdd(&whist[u3], w.w);
    }
    __syncthreads();
    for (int i = threadIdx.x; i < NRH; i += 256)
      pwsum[(size_t)c * NN + lo + i] = whist[i];
  }
}

// per-node: deg = sum over chunks (pdeg -> in-place exclusive chunk prefix),
// wsum = sum over chunks; also block-reduce deg -> bsum.
__global__ __launch_bounds__(256) void reduce_kernel(int* __restrict__ pdeg,
                                                     const float* __restrict__ pwsum,
                                                     int* __restrict__ deg,
                                                     float* __restrict__ wsum,
                                                     int* __restrict__ bsum) {
  int node = blockIdx.x * 256 + threadIdx.x;
  int acc = 0; float wacc = 0.f;
  if (node < NN) {
    for (int c = 0; c < CC; ++c) {
      size_t idx = (size_t)c * NN + node;
      int t = pdeg[idx];
      pdeg[idx] = acc;        // exclusive prefix over chunks
      acc += t;
      wacc += pwsum[idx];
    }
    deg[node] = acc;
    wsum[node] = wacc;
  }
  __shared__ int red[256];
  red[threadIdx.x] = (node < NN) ? acc : 0;
  __syncthreads();
  for (int off = 128; off > 0; off >>= 1) {
    if (threadIdx.x < off) red[threadIdx.x] += red[threadIdx.x + off];
    __syncthreads();
  }
  if (threadIdx.x == 0) bsum[blockIdx.x] = red[0];
}

__global__ __launch_bounds__(256) void scan2_kernel(const int* __restrict__ bsum,
                                                    int* __restrict__ boff,
                                                    int* __restrict__ row_start, int nb, int n) {
  __shared__ int buf[256];
  int tid = threadIdx.x;
  int v = (tid < nb) ? bsum[tid] : 0;
  buf[tid] = v;
  __syncthreads();
  for (int off = 1; off < 256; off <<= 1) {
    int t = (tid >= off) ? buf[tid - off] : 0;
    __syncthreads();
    buf[tid] += t;
    __syncthreads();
  }
  if (tid < nb) boff[tid] = buf[tid] - v;  // exclusive prefix
  if (tid == 255) row_start[n] = buf[255];
}

__global__ __launch_bounds__(256) void scan3_kernel(const int* __restrict__ deg,
                                                    const int* __restrict__ boff,
                                                    int* __restrict__ row_start, int n) {
  __shared__ int buf[256];
  int tid = threadIdx.x;
  int i = blockIdx.x * 256 + tid;
  int v = (i < n) ? deg[i] : 0;
  buf[tid] = v;
  __syncthreads();
  for (int off = 1; off < 256; off <<= 1) {
    int t = (tid >= off) ? buf[tid - off] : 0;
    __syncthreads();
    buf[tid] += t;
    __syncthreads();
  }
  if (i < n) row_start[i] = boff[blockIdx.x] + buf[tid] - v;
}

__global__ __launch_bounds__(256) void csr_fill_kernel(const int* __restrict__ ei,
                                                       const float* __restrict__ ew,
                                                       const float* __restrict__ wsum,
                                                       const int* __restrict__ row_start,
                                                       const int* __restrict__ pdeg_excl,
                                                       const int* __restrict__ rank,
                                                       int2* __restrict__ csr, int e_cnt) {
  int e = blockIdx.x * 256 + threadIdx.x;
  if (e >= e_cnt) return;
  int c = e / CH;
  int src = ei[e], dst = ei[EE + e];
  float ws = wsum[src];
  ws = ws < 1.f ? 1.f : ws;
  float v = 0.9f * ew[e] / ws;            // (1-ALPHA) * enorm folded together
  int pos = row_start[dst] + pdeg_excl[(size_t)c * NN + dst] + rank[e];
  csr[pos] = make_int2(src, __float_as_int(v));
}

// ---------------- propagation: one wave per node, fp16 h, half2 per lane ----------------
// CSR walked in 8-edge scalar batches, software-pipelined: next batch's s_loads
// issue while current batch's 8 row-gathers are in flight. (R7-proven version.)
__global__ __launch_bounds__(256) void prop_kernel(const __half* __restrict__ h_cur,
                                                   const __half* __restrict__ base,
                                                   const int* __restrict__ row_start,
                                                   const long* __restrict__ csr,
                                                   __half* __restrict__ h_next) {
  int node = __builtin_amdgcn_readfirstlane((int)blockIdx.x * 4 + (int)(threadIdx.x >> 6));
  if (node >= NN) return;
  int lane = threadIdx.x & 63;
  const __half2* hc = (const __half2*)h_cur;
  float2 b = __half22float2(((const __half2*)base)[(size_t)node * 64 + lane]);
  float ax = 0.1f * b.x, ay = 0.1f * b.y;   // ALPHA * base
  float bx = 0.f, by = 0.f;
  int s = row_start[node], e = row_start[node + 1];
  int nfull = (e - s) >> 3;
  int i = s;
  if (nfull > 0) {
    long cur[8];
#pragma unroll
    for (int j = 0; j < 8; ++j) cur[j] = csr[i + j];
    i += 8;
    for (int bidx = 1; bidx < nfull; ++bidx) {
      long nxt[8];
#pragma unroll
      for (int j = 0; j < 8; ++j) nxt[j] = csr[i + j];
      i += 8;
      float2 g[8];
#pragma unroll
      for (int j = 0; j < 8; ++j) g[j] = __half22float2(hc[(size_t)(int)cur[j] * 64 + lane]);
#pragma unroll
      for (int j = 0; j < 8; ++j) {
        float v = __int_as_float((int)(cur[j] >> 32));
        if (j & 1) { bx = fmaf(v, g[j].x, bx); by = fmaf(v, g[j].y, by); }
        else       { ax = fmaf(v, g[j].x, ax); ay = fmaf(v, g[j].y, ay); }
      }
#pragma unroll
      for (int j = 0; j < 8; ++j) cur[j] = nxt[j];
    }
    float2 g[8];
#pragma unroll
    for (int j = 0; j < 8; ++j) g[j] = __half22float2(hc[(size_t)(int)cur[j] * 64 + lane]);
#pragma unroll
    for (int j = 0; j < 8; ++j) {
      float v = __int_as_float((int)(cur[j] >> 32));
      if (j & 1) { bx = fmaf(v, g[j].x, bx); by = fmaf(v, g[j].y, by); }
      else       { ax = fmaf(v, g[j].x, ax); ay = fmaf(v, g[j].y, ay); }
    }
  }
  for (; i < e; ++i) {
    long c0 = csr[i];
    float2 g0 = __half22float2(hc[(size_t)(int)c0 * 64 + lane]);
    float v = __int_as_float((int)(c0 >> 32));
    ax = fmaf(v, g0.x, ax); ay = fmaf(v, g0.y, ay);
  }
  ((__half2*)h_next)[(size_t)node * 64 + lane] =
      __float22half2_rn(make_float2(ax + bx, ay + by));
}

// ---------------- MFMA dense: out[n][j] = act(sum_k X[n][k] * W[j][k] + ...) -------------
template <int K, int KA, int JP, int JR, int ACT, bool RESID, typename IT, typename OT>
__global__ __launch_bounds__(256) void mfma_dense(
    const IT* __restrict__ Xa, const IT* __restrict__ Xb,
    const float* __restrict__ W, const float* __restrict__ lb,
    const float* __restrict__ bg, const float* __restrict__ bb,
    const float* __restrict__ bm, const float* __restrict__ bv,
    const OT* __restrict__ resid, OT* __restrict__ out) {
  constexpr int KC = (K > 128) ? 128 : K;
  static_assert(K % KC == 0 && KC % 32 == 0 && JP % 16 == 0, "");
  constexpr int JT = JP / 16;
  __shared__ _Float16 xL[128][KC + 8];
  __shared__ _Float16 wL[JP][KC + 8];
  const int tid = threadIdx.x;
  const int wv = tid >> 6, lane = tid & 63;
  const int q = lane >> 4, m = lane & 15;
  const int r0 = blockIdx.x * 128;

  floatx4 acc[2][JT];
#pragma unroll
  for (int rt = 0; rt < 2; ++rt)
#pragma unroll
    for (int jt = 0; jt < JT; ++jt) acc[rt][jt] = (floatx4)(0.f);

  for (int kc = 0; kc < K; kc += KC) {
    __syncthreads();
    // stage X: 128 rows x KC cols, fp16
    for (int idx = tid; idx < 128 * (KC / 4); idx += 256) {
      int r = idx / (KC / 4);
      int c4 = (idx % (KC / 4)) * 4;
      int row = r0 + r;
      int col = kc + c4;
      float4 v = make_float4(0.f, 0.f, 0.f, 0.f);
      if (row < NN) {
        if (col < KA) v = ld4(&Xa[(size_t)row * KA + col]);
        else          v = ld4(&Xb[(size_t)row * (K - KA) + (col - KA)]);
      }
      xL[r][c4 + 0] = (_Float16)v.x; xL[r][c4 + 1] = (_Float16)v.y;
      xL[r][c4 + 2] = (_Float16)v.z; xL[r][c4 + 3] = (_Float16)v.w;
    }
    // stage W: JP rows x KC cols, fp16 (zero-fill beyond JR)
    for (int idx = tid; idx < JP * (KC / 4); idx += 256) {
      int j = idx / (KC / 4);
      int c4 = (idx % (KC / 4)) * 4;
      float4 v = make_float4(0.f, 0.f, 0.f, 0.f);
      if (j < JR) v = *(const float4*)&W[(size_t)j * K + kc + c4];
      wL[j][c4 + 0] = (_Float16)v.x; wL[j][c4 + 1] = (_Float16)v.y;
      wL[j][c4 + 2] = (_Float16)v.z; wL[j][c4 + 3] = (_Float16)v.w;
    }
    __syncthreads();
#pragma unroll
    for (int ks = 0; ks < KC; ks += 32) {
      half8 a0 = *(const half8*)&xL[wv * 32 + m][ks + q * 8];
      half8 a1 = *(const half8*)&xL[wv * 32 + 16 + m][ks + q * 8];
#pragma unroll
      for (int jt = 0; jt < JT; ++jt) {
        half8 b = *(const half8*)&wL[jt * 16 + m][ks + q * 8];
        acc[0][jt] = __builtin_amdgcn_mfma_f32_16x16x32_f16(a0, b, acc[0][jt], 0, 0, 0);
        acc[1][jt] = __builtin_amdgcn_mfma_f32_16x16x32_f16(a1, b, acc[1][jt], 0, 0, 0);
      }
    }
  }
  // epilogue: lane holds col j = jt*16 + m, rows q*4 + reg (+16 per rt)
#pragma unroll
  for (int jt = 0; jt < JT; ++jt) {
    int j = jt * 16 + m;
    if (j >= JR) continue;
    float sc = 0.f, sh = 0.f;
    if (ACT == 1) {
      sc = bg[j] * rsqrtf(bv[j] + 1e-5f);
      sh = (lb[j] - bm[j]) * sc + bb[j];
    } else {
      sh = lb[j];
    }
#pragma unroll
    for (int rt = 0; rt < 2; ++rt) {
#pragma unroll
      for (int reg = 0; reg < 4; ++reg) {
        int row = r0 + wv * 32 + rt * 16 + q * 4 + reg;
        if (row >= NN) continue;
        float a = acc[rt][jt][reg];
        float y;
        if (ACT == 0)      y = a + sh;
        else if (ACT == 1) y = fmaxf(fmaf(a, sc, sh), 0.f);
        else               y = gelu_exact(a + sh);
        if (RESID) y += (float)resid[(size_t)row * JR + j];
        st1(&out[(size_t)row * JR + j], y);
      }
    }
  }
}

// ---------------- att2 (64 -> 11) + softmax, one thread per node ----------------
__global__ __launch_bounds__(64) void att2_softmax_kernel(const __half* __restrict__ g,
                                                          const float* __restrict__ W2,
                                                          const float* __restrict__ b2,
                                                          float* __restrict__ attw, int n_rows) {
  __shared__ float gl[64][65];
  int r0 = blockIdx.x * 64;
  for (int idx = threadIdx.x; idx < 64 * 16; idx += 64) {
    int r = idx >> 4, c4 = (idx & 15) * 4;
    float4 v = make_float4(0.f, 0.f, 0.f, 0.f);
    if (r0 + r < n_rows) v = ld4(&g[(size_t)(r0 + r) * 64 + c4]);
    gl[r][c4] = v.x; gl[r][c4 + 1] = v.y; gl[r][c4 + 2] = v.z; gl[r][c4 + 3] = v.w;
  }
  __syncthreads();
  int r = threadIdx.x;
  int n = r0 + r;
  if (n >= n_rows) return;
  float a[KIT + 1];
#pragma unroll
  for (int j = 0; j < KIT + 1; ++j) {
    float acc = b2[j];
#pragma unroll
    for (int k = 0; k < 64; ++k) acc = fmaf(gl[r][k], W2[j * 64 + k], acc);
    a[j] = acc;
  }
  float mx = a[0];
#pragma unroll
  for (int j = 1; j < KIT + 1; ++j) mx = fmaxf(mx, a[j]);
  float s = 0.f;
#pragma unroll
  for (int j = 0; j < KIT + 1; ++j) { a[j] = expf(a[j] - mx); s += a[j]; }
  float inv = 1.f / s;
#pragma unroll
  for (int j = 0; j < KIT + 1; ++j) attw[n * 16 + j] = a[j] * inv;
}

// ---------------- fuse: fused[n][128] = sum_k attw[n][k] * XS_k[n] (fp16) ----------------
__global__ __launch_bounds__(256) void fused_gather_kernel(const __half* __restrict__ XS,
                                                           const float* __restrict__ attw,
                                                           __half* __restrict__ fused) {
  int node = __builtin_amdgcn_readfirstlane((int)blockIdx.x * 4 + (int)(threadIdx.x >> 6));
  if (node >= NN) return;
  int lane = threadIdx.x & 63;
  float ax = 0.f, ay = 0.f;
#pragma unroll
  for (int k = 0; k <= KIT; ++k) {
    float wk = attw[node * 16 + k];   // wave-uniform -> s_load
    float2 v = __half22float2(((const __half2*)(XS + (size_t)k * NHF))[(size_t)node * 64 + lane]);
    ax = fmaf(wk, v.x, ax);
    ay = fmaf(wk, v.y, ay);
  }
  ((__half2*)fused)[(size_t)node * 64 + lane] = __float22half2_rn(make_float2(ax, ay));
}

// recompute-path variant: fused (+)= attw[:,k] * h (h fp16, fused fp32 for accumulation)
__global__ __launch_bounds__(256) void fused_accum_kernel(const __half* __restrict__ h,
                                                          const float* __restrict__ attw,
                                                          float* __restrict__ fused, int k) {
  int node = __builtin_amdgcn_readfirstlane((int)blockIdx.x * 4 + (int)(threadIdx.x >> 6));
  if (node >= NN) return;
  int lane = threadIdx.x & 63;
  float wk = attw[node * 16 + k];
  float2 v = __half22float2(((const __half2*)h)[(size_t)node * 64 + lane]);
  float2 o;
  if (k == 0) {
    o = make_float2(wk * v.x, wk * v.y);
  } else {
    float2 f = ((const float2*)fused)[(size_t)node * 64 + lane];
    o = make_float2(fmaf(wk, v.x, f.x), fmaf(wk, v.y, f.y));
  }
  ((float2*)fused)[(size_t)node * 64 + lane] = o;
}

extern "C" void kernel_launch(void* const* d_in, const int* in_sizes, int n_in,
                              void* d_out, int out_size, void* d_ws, size_t ws_size,
                              hipStream_t stream) {
  (void)in_sizes; (void)n_in; (void)out_size;
  const float* x      = (const float*)d_in[0];
  const int*   ei     = (const int*)d_in[1];
  const float* ew     = (const float*)d_in[2];
  const float* lin1_w = (const float*)d_in[3];
  const float* lin1_b = (const float*)d_in[4];
  const float* bn1_g  = (const float*)d_in[5];
  const float* bn1_b  = (const float*)d_in[6];
  const float* bn1_m  = (const float*)d_in[7];
  const float* bn1_v  = (const float*)d_in[8];
  const float* lin2_w = (const float*)d_in[9];
  const float* lin2_b = (const float*)d_in[10];
  const float* bn2_g  = (const float*)d_in[11];
  const float* bn2_b  = (const float*)d_in[12];
  const float* bn2_m  = (const float*)d_in[13];
  const float* bn2_v  = (const float*)d_in[14];
  const float* att1_w = (const float*)d_in[15];
  const float* att1_b = (const float*)d_in[16];
  const float* att2_w = (const float*)d_in[17];
  const float* att2_b = (const float*)d_in[18];
  const float* head1_w= (const float*)d_in[19];
  const float* head1_b= (const float*)d_in[20];
  const float* bn3_g  = (const float*)d_in[21];
  const float* bn3_b  = (const float*)d_in[22];
  const float* bn3_m  = (const float*)d_in[23];
  const float* bn3_v  = (const float*)d_in[24];
  const float* head2_w= (const float*)d_in[25];
  const float* head2_b= (const float*)d_in[26];
  float* out = (float*)d_out;

  char* p = (char*)d_ws;
  auto alloc = [&](size_t bytes) -> void* {
    void* r = (void*)p;
    p += (bytes + 255) & ~(size_t)255;
    return r;
  };
  // persistent buffers (live across whole launch)
  int*   row_start= (int*)alloc((size_t)(NN + 1) * 4);
  int*   bsum     = (int*)alloc((size_t)256 * 4);
  int*   boff     = (int*)alloc((size_t)256 * 4);
  int*   deg      = (int*)alloc((size_t)NN * 4);
  float* wsum     = (float*)alloc((size_t)NN * 4);
  long*  csr      = (long*)alloc((size_t)EE * 8);
  __half* gbuf    = (__half*)alloc((size_t)NN * 64 * 2);
  float* attw     = (float*)alloc((size_t)NN * 16 * 4);
  __half* h1      = (__half*)alloc((size_t)NHF * 2);
  __half* fusedH  = (__half*)alloc((size_t)NHF * 2);
  __half* zbuf    = (__half*)alloc((size_t)NN * 64 * 2);
  size_t common = (size_t)(p - (char*)d_ws);
  size_t stored_need = common + (size_t)(KIT + 1) * NHF * 2 + 4096;
  bool stored = ws_size >= stored_need;

  // preprocessing temporaries: pdeg (12.8MB) + pwsum (12.8MB) + rank (3.2MB).
  // In the stored path they OVERLAY the XS[8..10] snapshot region (38.4MB), which
  // is dead until prop iteration k=7 -- all on one stream, so this is safe.
  __half* XS = nullptr;
  int* pdeg; float* pwsum; int* rank;
  if (stored) {
    XS = (__half*)alloc((size_t)(KIT + 1) * NHF * 2);
    char* ovl = (char*)(XS + (size_t)8 * NHF);
    pdeg  = (int*)ovl;
    pwsum = (float*)(ovl + (size_t)CC * NN * 4);
    rank  = (int*)(ovl + 2 * (size_t)CC * NN * 4);
  } else {
    pdeg  = (int*)alloc((size_t)CC * NN * 4);
    pwsum = (float*)alloc((size_t)CC * NN * 4);
    rank  = (int*)alloc((size_t)EE * 4);
  }

  const int GE  = (EE + 255) / 256;          // edge-parallel grid
  const int GN  = (NN + 255) / 256;          // node-parallel grid (196)
  const int GM  = (NN + 127) / 128;          // mfma dense grid (391)
  const int GP  = (NN + 3) / 4;              // wave-per-node grids (12500)
  const int GA  = (NN + 63) / 64;            // att2 grid

  // graph preprocessing (atomic-free)
  hist2_kernel<<<dim3(CC, 2 * RRH), 256, 0, stream>>>(ei, ew, pdeg, pwsum, rank);
  reduce_kernel<<<GN, 256, 0, stream>>>(pdeg, pwsum, deg, wsum, bsum);
  scan2_kernel<<<1, 256, 0, stream>>>(bsum, boff, row_start, GN, NN);
  scan3_kernel<<<GN, 256, 0, stream>>>(deg, boff, row_start, NN);
  csr_fill_kernel<<<GE, 256, 0, stream>>>(ei, ew, wsum, row_start, pdeg, rank,
                                          (int2*)csr, EE);

  if (stored) {
    mfma_dense<128, 128, 128, 128, 1, false, float, __half><<<GM, 256, 0, stream>>>(
        x, (const float*)nullptr, lin1_w, lin1_b, bn1_g, bn1_b, bn1_m, bn1_v, nullptr, h1);
    mfma_dense<128, 128, 128, 128, 1, true, __half, __half><<<GM, 256, 0, stream>>>(
        h1, (const __half*)nullptr, lin2_w, lin2_b, bn2_g, bn2_b, bn2_m, bn2_v, h1, XS);
    for (int k = 0; k < KIT; ++k) {
      prop_kernel<<<GP, 256, 0, stream>>>(XS + (size_t)k * NHF, XS, row_start,
                                          csr, XS + (size_t)(k + 1) * NHF);
    }
    mfma_dense<256, 128, 64, 64, 2, false, __half, __half><<<GM, 256, 0, stream>>>(
        XS, XS + (size_t)KIT * NHF, att1_w, att1_b, nullptr, nullptr, nullptr, nullptr,
        nullptr, gbuf);
    att2_softmax_kernel<<<GA, 64, 0, stream>>>(gbuf, att2_w, att2_b, attw, NN);
    fused_gather_kernel<<<GP, 256, 0, stream>>>(XS, attw, fusedH);
    mfma_dense<128, 128, 64, 64, 1, false, __half, __half><<<GM, 256, 0, stream>>>(
        fusedH, (const __half*)nullptr, head1_w, head1_b, bn3_g, bn3_b, bn3_m, bn3_v,
        nullptr, zbuf);
  } else {
    float*  fusedF = (float*)alloc((size_t)NHF * 4);
    __half* base   = (__half*)alloc((size_t)NHF * 2);
    __half* hA     = (__half*)alloc((size_t)NHF * 2);
    __half* hB     = (__half*)alloc((size_t)NHF * 2);
    mfma_dense<128, 128, 128, 128, 1, false, float, __half><<<GM, 256, 0, stream>>>(
        x, (const float*)nullptr, lin1_w, lin1_b, bn1_g, bn1_b, bn1_m, bn1_v, nullptr, h1);
    mfma_dense<128, 128, 128, 128, 1, true, __half, __half><<<GM, 256, 0, stream>>>(
        h1, (const __half*)nullptr, lin2_w, lin2_b, bn2_g, bn2_b, bn2_m, bn2_v, h1, base);
    // pass 1: get xs10
    const __half* cur = base;
    for (int k = 1; k <= KIT; ++k) {
      __half* nxt = (k & 1) ? hA : hB;
      prop_kernel<<<GP, 256, 0, stream>>>(cur, base, row_start, csr, nxt);
      cur = nxt;
    }
    mfma_dense<256, 128, 64, 64, 2, false, __half, __half><<<GM, 256, 0, stream>>>(
        base, cur, att1_w, att1_b, nullptr, nullptr, nullptr, nullptr, nullptr, gbuf);
    att2_softmax_kernel<<<GA, 64, 0, stream>>>(gbuf, att2_w, att2_b, attw, NN);
    // pass 2: re-propagate, accumulate fused on the fly (fp32 accumulator)
    fused_accum_kernel<<<GP, 256, 0, stream>>>(base, attw, fusedF, 0);
    cur = base;
    for (int k = 1; k <= KIT; ++k) {
      __half* nxt = (k & 1) ? hA : hB;
      prop_kernel<<<GP, 256, 0, stream>>>(cur, base, row_start, csr, nxt);
      fused_accum_kernel<<<GP, 256, 0, stream>>>(nxt, attw, fusedF, k);
      cur = nxt;
    }
    mfma_dense<128, 128, 64, 64, 1, false, float, __half><<<GM, 256, 0, stream>>>(
        fusedF, (const float*)nullptr, head1_w, head1_b, bn3_g, bn3_b, bn3_m, bn3_v,
        nullptr, zbuf);
  }

  // head2 (z fp16 -> out fp32)
  mfma_dense<64, 64, 48, 40, 0, false, __half, float><<<GM, 256, 0, stream>>>(
      zbuf, (const __half*)nullptr, head2_w, head2_b, nullptr, nullptr, nullptr, nullptr,
      nullptr, out);
}